// Round 10
// baseline (266.975 us; speedup 1.0000x reference)
//
#include <hip/hip_runtime.h>

// NODEModel MFMA fp16, R10: 4 waves/SIMD via register diet.
// 32-sample waves (acc 8x2 f32x4 = 64 AGPR), H 32KB + W-ring 2x4KB = 40KB
// -> 4 blocks/CU. launch_bounds(256,4) => 128 regs/wave = 64 VGPR + 64 AGPR.
// VGPR diet: input features kept as ready f16x8 B-templates (prep reorders ic
// input rows into the dp layout: k=0 unused/zero-row, feats k=1..5, bias k=6);
// XOR-swizzle addrs decomposed to 2 persistent regs each:
//   waddr(mt) = K + ((mt<<5) ^ dh32), raddr(ks) = Kr + ((ks<<6) ^ dk64);
// A-frag reads = lane*16 reg + compile-time ds offset (4KB slabs, slab pairs
// unrolled so ring slot is compile-time). Sync per slab = R8's proven
// s_waitcnt(vm0,lgkm0) + raw s_barrier; stage next slab right after barrier.

#define NTHREADS 256
#define MLP_STRIDE 53248   // fp16 elems per MLP: 4096 WinA + 3*16384 Wh
#define WINA_ELEMS 4096
#define WH_ELEMS 16384
#define TANH_SCALE 2.8853900817779268f   // 2*log2(e)

// LDS map: [0,32768) H ; [32768,36864) W slot0 ; [36864,40960) W slot1
#define LDS_W0 32768
#define LDS_W1 36864

typedef _Float16 f16;
typedef f16 f16x8 __attribute__((ext_vector_type(8)));
typedef __fp16 fp16x2 __attribute__((ext_vector_type(2)));
typedef float f32x4 __attribute__((ext_vector_type(4)));

// ---------------- prep: fp32 weights -> fp16 fragment-linear (pre-scaled) ----
// ic input rows remapped to dp layout: k=0 -> 0, k=1..5 -> Win[k-1], k=6 -> bin.
__global__ __launch_bounds__(NTHREADS)
void prep_kernel(const float* __restrict__ dp_Win, const float* __restrict__ dp_bin,
                 const float* __restrict__ dp_Wh,  const float* __restrict__ dp_bh,
                 const float* __restrict__ ic_Win, const float* __restrict__ ic_bin,
                 const float* __restrict__ ic_Wh,  const float* __restrict__ ic_bh,
                 f16* __restrict__ wsw)
{
    int e = blockIdx.x * NTHREADS + threadIdx.x;
    if (e >= 2 * MLP_STRIDE + 768) return;
    if (e >= 2 * MLP_STRIDE) {          // scaled hidden biases, fp32
        int idx = e - 2 * MLP_STRIDE;   // [mlp(2)][l(3)][m(128)]
        int mlp = idx / 384, rem = idx % 384;
        const float* bh = mlp ? ic_bh : dp_bh;
        float* bsc = (float*)(wsw + 2 * MLP_STRIDE);
        bsc[idx] = bh[rem] * TANH_SCALE;
        return;
    }
    int mlp = (e >= MLP_STRIDE) ? 1 : 0;   // 0 = dp, 1 = ic
    int r = e - mlp * MLP_STRIDE;
    const float* Win = mlp ? ic_Win : dp_Win;
    const float* bin = mlp ? ic_bin : dp_bin;
    const float* Wh  = mlp ? ic_Wh  : dp_Wh;
    float val;
    if (r < WINA_ELEMS) {
        int mt = r >> 9, lane = (r >> 3) & 63, j = r & 7;
        int m = mt * 16 + (lane & 15);
        int k = ((lane >> 4) << 3) + j;                     // 0..31
        if (mlp) {  // ic remapped to dp-style layout
            val = (k >= 1 && k <= 5) ? Win[(k - 1) * 128 + m]
                : ((k == 6) ? bin[m] : 0.0f);
        } else {    // dp: feats k=0..5, bias k=6
            val = (k < 6) ? Win[k * 128 + m] : ((k == 6) ? bin[m] : 0.0f);
        }
    } else {
        int r2 = r - WINA_ELEMS;
        int l = r2 >> 14, r3 = r2 & 16383;
        int ks = r3 >> 12, mt = (r3 >> 9) & 7, lane = (r3 >> 3) & 63, j = r3 & 7;
        int m = mt * 16 + (lane & 15);
        int k = ks * 32 + ((lane >> 4) << 3) + j;           // 0..127
        val = Wh[(l * 128 + k) * 128 + m];
    }
    wsw[e] = (f16)(val * TANH_SCALE);
}

// ---------------- main ----------------
__device__ __forceinline__ float tanh_fast(float x) {
    // input pre-scaled by 2*log2e: tanh = 1 - 2/(exp2(x)+1)
    float e = __builtin_amdgcn_exp2f(x);
    float r = __builtin_amdgcn_rcpf(e + 1.0f);
    return fmaf(-2.0f, r, 1.0f);
}

__device__ __forceinline__ unsigned int pk16(float a, float b) {
    union { fp16x2 h; unsigned int u; } c;
    c.h = __builtin_amdgcn_cvt_pkrtz(a, b);
    return c.u;
}

__device__ __forceinline__ int h_addr(int n, int kb) {
    return n * 256 + ((((kb >> 4) ^ (n & 7)) << 4) | (kb & 15));
}

__device__ __forceinline__ f32x4 mfma16(f16x8 a, f16x8 b, f32x4 c) {
    return __builtin_amdgcn_mfma_f32_16x16x32_f16(a, b, c, 0, 0, 0);
}

__device__ __forceinline__ void stage16(const void* g, void* l) {
    __builtin_amdgcn_global_load_lds((const __attribute__((address_space(1))) void*)g,
                                     (__attribute__((address_space(3))) void*)l, 16, 0, 0);
}

#define WAITCNT_VM0_LGKM0 0x0070   // vmcnt=0, expcnt=7 (dc), lgkmcnt=0

__global__ __launch_bounds__(NTHREADS, 4)
void node_main(const float* __restrict__ tx, const f16* __restrict__ wsw,
               const float* __restrict__ dp_Wout, const float* __restrict__ dp_bout,
               const float* __restrict__ ic_Wout, const float* __restrict__ ic_bout,
               float* __restrict__ out)
{
    __shared__ __align__(16) unsigned char lds[40960];

    const int tid  = threadIdx.x;
    const int lane = tid & 63;
    const int wv   = tid >> 6;
    const int q    = lane >> 4;
    const int l15  = lane & 15;
    const int p0   = blockIdx.x * 128;
    const int n0   = wv * 32 + l15;
    const int d    = l15 & 7;

    // compact swizzle state (2+2 regs + base)
    const int basen = n0 * 256;
    const int K    = basen + ((q & 1) << 3) + ((((q >> 1) ^ d) & 1) << 4);
    const int dh32 = (d >> 1) << 5;
    const int Kr   = basen + ((q ^ (d & 3)) << 4);
    const int dk64 = (d >> 2) << 6;
    const int lane16 = lane << 4;

    const float* bsc = (const float*)(wsw + 2 * MLP_STRIDE);

    const float4* tx4 = (const float4*)tx;
    float4 t0v = tx4[p0 + n0];
    float4 t1v = tx4[p0 + n0 + 16];
    float4 tov = tx4[p0 + (tid >> 1)];

    // B templates: [0, r, x, y, z, i, 1, 0] (slot0 patched per dp chain)
    f16x8 bt0 = {}, bt1 = {};
    float a0, a1, ao, io;
    {
        float xx = t0v.y, yy = t0v.z, zz = t0v.w;
        float rr = sqrtf(fmaf(xx, xx, fmaf(yy, yy, zz * zz)));
        float irs = 1.0f / fmaxf(rr, 1e-8f);
        if (lane < 16) {
            bt0[1] = (f16)rr; bt0[2] = (f16)(xx * irs); bt0[3] = (f16)(yy * irs);
            bt0[4] = (f16)(zz * irs); bt0[5] = (f16)(1.0f / (1.0f + rr));
            bt0[6] = (f16)1.0f;
        }
        a0 = 0.5f * t0v.x;
    }
    {
        float xx = t1v.y, yy = t1v.z, zz = t1v.w;
        float rr = sqrtf(fmaf(xx, xx, fmaf(yy, yy, zz * zz)));
        float irs = 1.0f / fmaxf(rr, 1e-8f);
        if (lane < 16) {
            bt1[1] = (f16)rr; bt1[2] = (f16)(xx * irs); bt1[3] = (f16)(yy * irs);
            bt1[4] = (f16)(zz * irs); bt1[5] = (f16)(1.0f / (1.0f + rr));
            bt1[6] = (f16)1.0f;
        }
        a1 = 0.5f * t1v.x;
    }
    {
        float xx = tov.y, yy = tov.z, zz = tov.w;
        float rr = sqrtf(fmaf(xx, xx, fmaf(yy, yy, zz * zz)));
        io = 1.0f / (1.0f + rr);
        ao = 0.5f * tov.x;
    }

    const f32x4 z4 = {0.f, 0.f, 0.f, 0.f};
    float icv = 0.0f, dsum = 0.0f;

    // prologue: stage slab 0 of chain 0 (ic) into slot 0
    stage16((const char*)(wsw + MLP_STRIDE) + tid * 16, lds + LDS_W0 + tid * 16);

    #pragma unroll 1
    for (int c = 0; c < 4; ++c) {
        const f16* wb     = wsw + (c == 0 ? MLP_STRIDE : 0);
        const float* bb   = bsc + (c == 0 ? 384 : 0);
        const float* Wout = (c == 0) ? ic_Wout : dp_Wout;
        const float* bout = (c == 0) ? ic_bout : dp_bout;
        const float tn = (c == 1) ? 0.22540333075851662f
                       : ((c == 2) ? 1.0f : 1.7745966692414834f);   // node+1

        f16x8 b0 = bt0, b1 = bt1;
        if (c != 0) { b0[0] = (f16)(a0 * tn); b1[0] = (f16)(a1 * tn); }

        f32x4 acc[8][2];
        f16x8 hb0, hb1;          // persists across slab halves

        #pragma unroll 1
        for (int p2 = 0; p2 < 13; ++p2) {
            // ================= half A: slab s=2*p2, slot 0 =================
            __asm__ __volatile__("" ::: "memory");
            __builtin_amdgcn_s_waitcnt(WAITCNT_VM0_LGKM0);
            __builtin_amdgcn_s_barrier();
            __asm__ __volatile__("" ::: "memory");
            // stage slab 2*p2+1 -> slot 1 (always exists: <=25)
            stage16((const char*)(wb + (2 * p2 + 1) * 2048) + tid * 16,
                    lds + LDS_W1 + tid * 16);
            __asm__ __volatile__("" ::: "memory");

            if (p2 == 0) {
                // input layer, tiles mt 0..3 (K=32 complete in one MFMA)
                #pragma unroll
                for (int mtl = 0; mtl < 4; ++mtl) {
                    f16x8 a = *(const f16x8*)(lds + LDS_W0 + (mtl << 10) + lane16);
                    acc[mtl][0] = mfma16(a, b0, z4);
                    acc[mtl][1] = mfma16(a, b1, z4);
                }
                #pragma unroll
                for (int mtl = 0; mtl < 4; ++mtl) {
                    int wa = K + ((mtl << 5) ^ dh32);
                    #pragma unroll
                    for (int nt = 0; nt < 2; ++nt) {
                        f32x4 v = acc[mtl][nt];
                        uint2 o;
                        o.x = pk16(tanh_fast(v[0]), tanh_fast(v[1]));
                        o.y = pk16(tanh_fast(v[2]), tanh_fast(v[3]));
                        *(uint2*)(lds + wa + nt * 4096) = o;
                    }
                }
            } else {
                int idx = 2 * p2 - 2;
                int l = idx >> 3, ks = (idx >> 1) & 3;
                int ra = Kr + ((ks << 6) ^ dk64);
                hb0 = *(const f16x8*)(lds + ra);
                hb1 = *(const f16x8*)(lds + ra + 4096);
                if (ks == 0) {
                    const float* bl = bb + l * 128;
                    #pragma unroll
                    for (int mtl = 0; mtl < 4; ++mtl) {
                        f16x8 a = *(const f16x8*)(lds + LDS_W0 + (mtl << 10) + lane16);
                        f32x4 b4 = *(const f32x4*)(bl + mtl * 16 + q * 4);
                        acc[mtl][0] = mfma16(a, hb0, b4);
                        acc[mtl][1] = mfma16(a, hb1, b4);
                    }
                } else {
                    #pragma unroll
                    for (int mtl = 0; mtl < 4; ++mtl) {
                        f16x8 a = *(const f16x8*)(lds + LDS_W0 + (mtl << 10) + lane16);
                        acc[mtl][0] = mfma16(a, hb0, acc[mtl][0]);
                        acc[mtl][1] = mfma16(a, hb1, acc[mtl][1]);
                    }
                }
                if (ks == 3) {
                    #pragma unroll
                    for (int mtl = 0; mtl < 4; ++mtl) {
                        int wa = K + ((mtl << 5) ^ dh32);
                        #pragma unroll
                        for (int nt = 0; nt < 2; ++nt) {
                            f32x4 v = acc[mtl][nt];
                            uint2 o;
                            o.x = pk16(tanh_fast(v[0]), tanh_fast(v[1]));
                            o.y = pk16(tanh_fast(v[2]), tanh_fast(v[3]));
                            *(uint2*)(lds + wa + nt * 4096) = o;
                        }
                    }
                }
            }

            // ================= half B: slab s=2*p2+1, slot 1 =================
            __asm__ __volatile__("" ::: "memory");
            __builtin_amdgcn_s_waitcnt(WAITCNT_VM0_LGKM0);
            __builtin_amdgcn_s_barrier();
            __asm__ __volatile__("" ::: "memory");
            {
                int snext = 2 * p2 + 2;
                if (snext < 26)
                    stage16((const char*)(wb + snext * 2048) + tid * 16,
                            lds + LDS_W0 + tid * 16);
                else if (c < 3)   // next chain (dp) slab 0
                    stage16((const char*)wsw + tid * 16, lds + LDS_W0 + tid * 16);
            }
            __asm__ __volatile__("" ::: "memory");

            if (p2 == 0) {
                // input layer, tiles mt 4..7
                #pragma unroll
                for (int mtl = 0; mtl < 4; ++mtl) {
                    f16x8 a = *(const f16x8*)(lds + LDS_W1 + (mtl << 10) + lane16);
                    acc[4 + mtl][0] = mfma16(a, b0, z4);
                    acc[4 + mtl][1] = mfma16(a, b1, z4);
                }
                #pragma unroll
                for (int mtl = 0; mtl < 4; ++mtl) {
                    int wa = K + (((4 + mtl) << 5) ^ dh32);
                    #pragma unroll
                    for (int nt = 0; nt < 2; ++nt) {
                        f32x4 v = acc[4 + mtl][nt];
                        uint2 o;
                        o.x = pk16(tanh_fast(v[0]), tanh_fast(v[1]));
                        o.y = pk16(tanh_fast(v[2]), tanh_fast(v[3]));
                        *(uint2*)(lds + wa + nt * 4096) = o;
                    }
                }
            } else {
                int idx = 2 * p2 - 1;
                int l = idx >> 3, ks = (idx >> 1) & 3;
                if (ks == 0) {
                    const float* bl = bb + l * 128;
                    #pragma unroll
                    for (int mtl = 0; mtl < 4; ++mtl) {
                        f16x8 a = *(const f16x8*)(lds + LDS_W1 + (mtl << 10) + lane16);
                        f32x4 b4 = *(const f32x4*)(bl + (4 + mtl) * 16 + q * 4);
                        acc[4 + mtl][0] = mfma16(a, hb0, b4);
                        acc[4 + mtl][1] = mfma16(a, hb1, b4);
                    }
                } else {
                    #pragma unroll
                    for (int mtl = 0; mtl < 4; ++mtl) {
                        f16x8 a = *(const f16x8*)(lds + LDS_W1 + (mtl << 10) + lane16);
                        acc[4 + mtl][0] = mfma16(a, hb0, acc[4 + mtl][0]);
                        acc[4 + mtl][1] = mfma16(a, hb1, acc[4 + mtl][1]);
                    }
                }
                if (ks == 3) {
                    #pragma unroll
                    for (int mtl = 0; mtl < 4; ++mtl) {
                        int wa = K + (((4 + mtl) << 5) ^ dh32);
                        #pragma unroll
                        for (int nt = 0; nt < 2; ++nt) {
                            f32x4 v = acc[4 + mtl][nt];
                            uint2 o;
                            o.x = pk16(tanh_fast(v[0]), tanh_fast(v[1]));
                            o.y = pk16(tanh_fast(v[2]), tanh_fast(v[3]));
                            *(uint2*)(lds + wa + nt * 4096) = o;
                        }
                    }
                }
            }
        }

        // ---- output layer: VALU dot, 2 threads per sample (wave-local H) ----
        {
            int s  = tid >> 1;
            int hf = tid & 1;
            const float* wp = Wout + hf * 64;
            float sum = 0.0f;
            #pragma unroll
            for (int u = 0; u < 8; ++u) {
                f16x8 hv = *(const f16x8*)(lds + h_addr(s, hf * 128 + u * 16));
                f32x4 w0 = *(const f32x4*)(wp + u * 8);
                f32x4 w1 = *(const f32x4*)(wp + u * 8 + 4);
                sum = fmaf((float)hv[0], w0[0], sum);
                sum = fmaf((float)hv[1], w0[1], sum);
                sum = fmaf((float)hv[2], w0[2], sum);
                sum = fmaf((float)hv[3], w0[3], sum);
                sum = fmaf((float)hv[4], w1[0], sum);
                sum = fmaf((float)hv[5], w1[1], sum);
                sum = fmaf((float)hv[6], w1[2], sum);
                sum = fmaf((float)hv[7], w1[3], sum);
            }
            sum += __shfl_xor(sum, 1, 64);
            float val = sum + bout[0];
            if (c == 0) icv = val;
            else        dsum = fmaf((c == 2) ? (8.0f / 9.0f) : (5.0f / 9.0f), val, dsum);
        }
    }

    if ((tid & 1) == 0) {
        out[p0 + (tid >> 1)] = (icv + ao * dsum) * io;
    }
}

extern "C" void kernel_launch(void* const* d_in, const int* in_sizes, int n_in,
                              void* d_out, int out_size, void* d_ws, size_t ws_size,
                              hipStream_t stream) {
    const float* tx      = (const float*)d_in[0];
    const float* dp_Win  = (const float*)d_in[1];
    const float* dp_bin  = (const float*)d_in[2];
    const float* dp_Wh   = (const float*)d_in[3];
    const float* dp_bh   = (const float*)d_in[4];
    const float* dp_Wout = (const float*)d_in[5];
    const float* dp_bout = (const float*)d_in[6];
    const float* ic_Win  = (const float*)d_in[7];
    const float* ic_bin  = (const float*)d_in[8];
    const float* ic_Wh   = (const float*)d_in[9];
    const float* ic_bh   = (const float*)d_in[10];
    const float* ic_Wout = (const float*)d_in[11];
    const float* ic_bout = (const float*)d_in[12];
    float* out = (float*)d_out;
    f16* wsw = (f16*)d_ws;

    int n = in_sizes[0] / 4;

    prep_kernel<<<dim3((2 * MLP_STRIDE + 768 + NTHREADS - 1) / NTHREADS), dim3(NTHREADS), 0, stream>>>(
        dp_Win, dp_bin, dp_Wh, dp_bh, ic_Win, ic_bin, ic_Wh, ic_bh, wsw);

    node_main<<<dim3(n / 128), dim3(NTHREADS), 0, stream>>>(
        tx, wsw, dp_Wout, dp_bout, ic_Wout, ic_bout, out);
}